// Round 9
// baseline (568.165 us; speedup 1.0000x reference)
//
#include <hip/hip_runtime.h>

// VectorQuantizer: z [16,256,1024] fp32, emb [8192,256] fp32.
// out (FP32): [ z_q 4194304 | loss 1 | idx 16384 ]
// Ref emulation: d = fl(fl(s_z+s_e) - 2p), argmin w/ lowest-index ties.
// Fast path: split-bf16 (hi/lo) MFMA GEMM, barrier-free K-loop: A resident in LDS,
// B fragments loaded straight from frag-linear ws pages with depth-1 register
// prefetch (no ldsB, no per-kt barriers). Per-wave 32-col cell minima (64/row),
// top-4 fp64 fixup (validated R8). Fallback (small ws): round-5 fp32 path.

#define C_    256
#define T_    1024
#define M_    16384
#define N_    8192

#define OUT_ZQ   0
#define OUT_LOSS 4194304
#define OUT_IDX  4194305

// ---- ws layout, fast path ----
#define WS_SZ    0           // s_z [16384] float
#define WS_SE    16384       // s_e [8192] float
#define WS_PART  24576       // loss partials [256] float
#define MIN_OFF  131072u     // bytes: u64 minima [16384 rows][64 cells] = 8 MB
#define FB_OFF   8519680u    // bytes: frag-linear emb hi/lo, 8 MB
#define WS_NEED  16908288u   // bytes (proven available)
// ---- ws layout, fallback (round-5, known-PASS) ----
#define O_I1     24576
#define O_I2     40960
#define O_PART   73728

typedef __attribute__((ext_vector_type(8))) short bf16x8;
typedef __attribute__((ext_vector_type(4))) float f32x4;
typedef unsigned long long ull;

__device__ __forceinline__ unsigned short f2b(float f) {
    unsigned u = __float_as_uint(f);
    return (unsigned short)((u + 0x7FFFu + ((u >> 16) & 1u)) >> 16);   // RTNE
}
__device__ __forceinline__ float b2f(unsigned short u) {
    return __uint_as_float(((unsigned)u) << 16);
}

// ---------------- fused prep: emb frag-linear hi/lo + numpy pairwise sums ----------------
__global__ __launch_bounds__(256) void vq_prep(const float* __restrict__ z,
                                               const float* __restrict__ emb,
                                               float* __restrict__ ws,
                                               char* __restrict__ fb) {
    const int tid = threadIdx.x;
    if (blockIdx.x < 1024) {            // prep_b: emb -> fb
        int gid = blockIdx.x * 256 + tid;
        int n = gid >> 5, kg = gid & 31;
        const float* ep = emb + (size_t)n * C_ + kg * 8;
        unsigned hi[8], lo[8];
#pragma unroll
        for (int j = 0; j < 8; ++j) {
            float v = ep[j];
            unsigned short h = f2b(v);
            hi[j] = h;
            lo[j] = f2b(v - b2f(h));
        }
        int nt = n >> 4, kt = kg >> 2, lane = (kg & 3) * 16 + (n & 15);
        size_t base = ((size_t)((nt * 8 + kt) * 2) << 10) + (lane << 4);
        uint4 hv = {hi[0] | (hi[1] << 16), hi[2] | (hi[3] << 16), hi[4] | (hi[5] << 16), hi[6] | (hi[7] << 16)};
        uint4 lv = {lo[0] | (lo[1] << 16), lo[2] | (lo[3] << 16), lo[4] | (lo[5] << 16), lo[6] | (lo[7] << 16)};
        *(uint4*)(fb + base) = hv;
        *(uint4*)(fb + base + 1024) = lv;
    } else {                            // sums: numpy pairwise_sum replication
        int gid = (blockIdx.x - 1024) * 256 + tid;
        if (gid < M_) {
            int b = gid >> 10, t = gid & (T_ - 1);
            const float* zp = z + (size_t)b * C_ * T_ + t;
            float blk[2];
#pragma unroll
            for (int h = 0; h < 2; ++h) {
                float r[8];
#pragma unroll
                for (int j = 0; j < 8; ++j) {
                    float v = zp[(size_t)(h * 128 + j) * T_];
                    r[j] = __fmul_rn(v, v);
                }
                for (int i = 8; i < 128; i += 8)
#pragma unroll
                    for (int j = 0; j < 8; ++j) {
                        float v = zp[(size_t)(h * 128 + i + j) * T_];
                        r[j] = __fadd_rn(r[j], __fmul_rn(v, v));
                    }
                blk[h] = __fadd_rn(__fadd_rn(__fadd_rn(r[0], r[1]), __fadd_rn(r[2], r[3])),
                                   __fadd_rn(__fadd_rn(r[4], r[5]), __fadd_rn(r[6], r[7])));
            }
            ws[WS_SZ + gid] = __fadd_rn(blk[0], blk[1]);
        } else if (gid < M_ + N_) {
            int n = gid - M_;
            const float* ep = emb + (size_t)n * C_;
            float blk[2];
#pragma unroll
            for (int h = 0; h < 2; ++h) {
                float r[8];
#pragma unroll
                for (int j = 0; j < 8; ++j) {
                    float v = ep[h * 128 + j];
                    r[j] = __fmul_rn(v, v);
                }
                for (int i = 8; i < 128; i += 8)
#pragma unroll
                    for (int j = 0; j < 8; ++j) {
                        float v = ep[h * 128 + i + j];
                        r[j] = __fadd_rn(r[j], __fmul_rn(v, v));
                    }
                blk[h] = __fadd_rn(__fadd_rn(__fadd_rn(r[0], r[1]), __fadd_rn(r[2], r[3])),
                                   __fadd_rn(__fadd_rn(r[4], r[5]), __fadd_rn(r[6], r[7])));
            }
            ws[WS_SE + n] = __fadd_rn(blk[0], blk[1]);
        }
    }
}

// ---------------- pass1: barrier-free MFMA GEMM, B direct-from-L2 ----------------
// grid (256, 2), block 256 = 4 waves; wave = 64m x 32n (mt=4, nt4=2), waves span n.
__global__ __launch_bounds__(256, 2) void vq_mfma3(
        const float* __restrict__ z, const char* __restrict__ fb,
        const float* __restrict__ sz, const float* __restrict__ se,
        ull* __restrict__ minima) {
    __shared__ __align__(16) char ldsA[65536];   // 64m x 256k hi/lo, frag-linear

    const int tid = threadIdx.x;
    const int lane = tid & 63;
    const int wn = tid >> 6;                      // wave owns n-slice
    const int quad = lane >> 4, li = lane & 15;
    const int mb = blockIdx.x, ns = blockIdx.y;

    // ---- one-time A staging: z[b][c][t0..t0+64) -> hi/lo frag-linear LDS ----
    {
        const float* zb = z + (size_t)(mb >> 4) * C_ * T_ + ((mb & 15) << 6);
#pragma unroll
        for (int p = 0; p < 4; ++p) {
            int c  = p * 64 + (tid >> 2);
            int tq = tid & 3;
            const float* src = zb + (size_t)c * T_ + tq * 16;
            int kt = c >> 5, kg3 = (c >> 3) & 3, j = c & 7;
            unsigned short* d0 = (unsigned short*)(ldsA + (((tq * 8 + kt) * 2 + 0) << 10) + (kg3 << 8) + (j << 1));
            unsigned short* d1 = (unsigned short*)(ldsA + (((tq * 8 + kt) * 2 + 1) << 10) + (kg3 << 8) + (j << 1));
#pragma unroll
            for (int u = 0; u < 4; ++u) {
                float4 v = *(const float4*)(src + u * 4);
                float vv[4] = {v.x, v.y, v.z, v.w};
#pragma unroll
                for (int e = 0; e < 4; ++e) {
                    unsigned short h = f2b(vv[e]);
                    unsigned short l = f2b(vv[e] - b2f(h));
                    int i = u * 4 + e;
                    d0[i * 8] = h;
                    d1[i * 8] = l;
                }
            }
        }
    }
    __syncthreads();                     // the ONLY barrier

    float szr[16];
#pragma unroll
    for (int mt = 0; mt < 4; ++mt)
#pragma unroll
        for (int r = 0; r < 4; ++r)
            szr[mt * 4 + r] = sz[(mb << 6) + (mt << 4) + (quad << 2) + r];

    ull key[16];
#pragma unroll
    for (int s = 0; s < 16; ++s) key[s] = ~0ULL;

    const char* fbl = fb + (lane << 4);
    // B page for (nt,kt,q): ntile = ns*256 + nt*8 + wn*2 + (q>>1), h = q&1
#define BPTR(nt_, kt_, q_) ((const bf16x8*)(fbl + \
        ((((size_t)(ns * 256 + (nt_) * 8 + wn * 2 + ((q_) >> 1)) * 8 + (kt_)) * 2 + ((q_) & 1)) << 10)))

    bf16x8 bcur[4];
#pragma unroll
    for (int q = 0; q < 4; ++q) bcur[q] = *BPTR(0, 0, q);

    for (int nt = 0; nt < 32; ++nt) {
        f32x4 acc[4][2];
#pragma unroll
        for (int i = 0; i < 4; ++i)
#pragma unroll
            for (int j = 0; j < 2; ++j) acc[i][j] = (f32x4){0.f, 0.f, 0.f, 0.f};

#pragma unroll
        for (int kt = 0; kt < 8; ++kt) {
            // depth-1 prefetch (wraps at the very end; harmless re-read)
            bf16x8 bnext[4];
            const int pnt = (kt == 7) ? ((nt + 1) & 31) : nt;
            const int pkt = (kt + 1) & 7;
#pragma unroll
            for (int q = 0; q < 4; ++q) bnext[q] = *BPTR(pnt, pkt, q);

            bf16x8 a[4][2];
#pragma unroll
            for (int mt = 0; mt < 4; ++mt) {
                a[mt][0] = *(const bf16x8*)(ldsA + (((mt * 8 + kt) * 2 + 0) << 10) + (lane << 4));
                a[mt][1] = *(const bf16x8*)(ldsA + (((mt * 8 + kt) * 2 + 1) << 10) + (lane << 4));
            }
#pragma unroll
            for (int nt4 = 0; nt4 < 2; ++nt4) {
                const bf16x8 bh = bcur[nt4 * 2 + 0];
                const bf16x8 bl = bcur[nt4 * 2 + 1];
#pragma unroll
                for (int mt = 0; mt < 4; ++mt) {
                    f32x4 c = acc[mt][nt4];
                    c = __builtin_amdgcn_mfma_f32_16x16x32_bf16(a[mt][0], bh, c, 0, 0, 0);
                    c = __builtin_amdgcn_mfma_f32_16x16x32_bf16(a[mt][0], bl, c, 0, 0, 0);
                    c = __builtin_amdgcn_mfma_f32_16x16x32_bf16(a[mt][1], bh, c, 0, 0, 0);
                    acc[mt][nt4] = c;
                }
            }
#pragma unroll
            for (int q = 0; q < 4; ++q) bcur[q] = bnext[q];
        }

        // epilogue: quantized ref-formula score -> packed u64 running min
#pragma unroll
        for (int nt4 = 0; nt4 < 2; ++nt4) {
            const int ncol = ((ns * 256 + nt * 8 + wn * 2 + nt4) << 4) + li;
            const float sev = se[ncol];
#pragma unroll
            for (int mt = 0; mt < 4; ++mt) {
                f32x4 c = acc[mt][nt4];
#pragma unroll
                for (int r = 0; r < 4; ++r) {
                    float s = fmaf(-2.f, c[r], __fadd_rn(szr[mt * 4 + r], sev));
                    ull k = ((ull)__float_as_uint(s) << 32) | (unsigned)ncol;
                    const int sl = mt * 4 + r;
                    if (k < key[sl]) key[sl] = k;
                }
            }
        }
        if ((nt & 3) == 3) {             // flush cell (wave's 32 cols x 4 nt-iters)
            const int cell = ns * 32 + (nt >> 2) * 4 + wn;
#pragma unroll
            for (int sl = 0; sl < 16; ++sl) {
                ull kk = key[sl];
#pragma unroll
                for (int off = 1; off <= 8; off <<= 1) {
                    ull o = __shfl_xor(kk, off, 64);
                    if (o < kk) kk = o;
                }
                if (li == 0) {
                    int row = (mb << 6) + ((sl >> 2) << 4) + (quad << 2) + (sl & 3);
                    minima[(size_t)row * 64 + cell] = kk;
                }
                key[sl] = ~0ULL;
            }
        }
    }
#undef BPTR
}

// ---------------- pass2: top-4 of 64 cells + fp64 fixup + idx out ----------------
__global__ __launch_bounds__(256) void vq_pick2(
        const float* __restrict__ z, const float* __restrict__ emb,
        const float* __restrict__ ws, const ull* __restrict__ minima,
        float* __restrict__ out) {
    __shared__ float Lz[256 * 17];
    const float* sz = ws + WS_SZ;
    const float* se = ws + WS_SE;
    const int tid = threadIdx.x;
    const int w = tid >> 6, lane = tid & 63, li = lane & 15;
    const int m0 = blockIdx.x * 16;
    const int b = m0 >> 10, t0 = m0 & (T_ - 1);

    {
        const float* src = z + (size_t)b * C_ * T_ + (size_t)tid * T_ + t0;
#pragma unroll
        for (int u = 0; u < 4; ++u) {
            float4 v = *(const float4*)(src + u * 4);
            Lz[tid * 17 + u * 4 + 0] = v.x;
            Lz[tid * 17 + u * 4 + 1] = v.y;
            Lz[tid * 17 + u * 4 + 2] = v.z;
            Lz[tid * 17 + u * 4 + 3] = v.w;
        }
    }
    __syncthreads();

    for (int rr = 0; rr < 4; ++rr) {
        const int tloc = w * 4 + rr;
        const int m = m0 + tloc;
        ull kmin = minima[(size_t)m * 64 + lane];
        int cand[4];
#pragma unroll
        for (int rep = 0; rep < 4; ++rep) {
            ull bf = kmin;
#pragma unroll
            for (int off = 1; off <= 32; off <<= 1) {
                ull o = __shfl_xor(bf, off, 64);
                if (o < bf) bf = o;
            }
            int ix = (int)(unsigned)(bf & 0xFFFFFFFFull);
            cand[rep] = ix < 0 ? 0 : (ix > N_ - 1 ? N_ - 1 : ix);
            if (kmin == bf) kmin = ~0ULL;
        }
        const int cn = cand[lane >> 4];
        const float* ep = emb + (size_t)cn * C_;
        double sum = 0.0;
#pragma unroll
        for (int cc = 0; cc < 16; ++cc) {
            int c = cc * 16 + li;
            sum = fma((double)Lz[c * 17 + tloc], (double)ep[c], sum);
        }
#pragma unroll
        for (int off = 1; off <= 8; off <<= 1)
            sum += __shfl_xor(sum, off, 64);
        double s0 = __shfl(sum, 0, 64), s1 = __shfl(sum, 16, 64);
        double s2 = __shfl(sum, 32, 64), s3 = __shfl(sum, 48, 64);
        if (lane == 0) {
            float szm = sz[m];
            float d0 = fmaf(-2.f, (float)s0, __fadd_rn(szm, se[cand[0]]));
            float d1 = fmaf(-2.f, (float)s1, __fadd_rn(szm, se[cand[1]]));
            float d2 = fmaf(-2.f, (float)s2, __fadd_rn(szm, se[cand[2]]));
            float d3 = fmaf(-2.f, (float)s3, __fadd_rn(szm, se[cand[3]]));
            float bd = d0; int bi = cand[0];
            if (d1 < bd || (d1 == bd && cand[1] < bi)) { bd = d1; bi = cand[1]; }
            if (d2 < bd || (d2 == bd && cand[2] < bi)) { bd = d2; bi = cand[2]; }
            if (d3 < bd || (d3 == bd && cand[3] < bi)) { bd = d3; bi = cand[3]; }
            out[OUT_IDX + m] = (float)bi;
        }
    }
}

// ---------------- fallback round-5 pass1/pass2 (known-PASS) ----------------
__global__ __launch_bounds__(256) void vq_pass1_fp32(
        const float* __restrict__ z,
        const float* __restrict__ emb,
        float* __restrict__ ws) {
    __shared__ float As[32][68];
    __shared__ float Bs[32][68];
    const float* s_z = ws + WS_SZ;
    const float* s_e = ws + WS_SE;
    int* i1ws = (int*)ws + O_I1;
    int* i2ws = (int*)ws + O_I2;
    const int tid = threadIdx.x;
    const int mt  = blockIdx.x;
    const int tx  = tid & 15, ty = tid >> 4;
    const int b   = mt >> 4;
    const int t0  = (mt << 6) & (T_ - 1);
    const float* zbase = z + (size_t)b * C_ * T_ + t0;
    const int a_k = tid >> 4;
    const int a_m = (tid & 15) << 2;
    const int b_j = tid >> 2;
    const int b_q = (tid & 3) << 3;
    const float4 sz4 = *(const float4*)(s_z + mt * 64 + (ty << 2));
    const float szv[4] = {sz4.x, sz4.y, sz4.z, sz4.w};
    float v1[4], v2[4];
    int   i1[4], i2[4];
#pragma unroll
    for (int i = 0; i < 4; ++i) {
        v1[i] = INFINITY; v2[i] = INFINITY;
        i1[i] = 0x7FFFFFFF; i2[i] = 0x7FFFFFFF;
    }
    for (int nt = 0; nt < N_ / 64; ++nt) {
        const int n0 = nt * 64;
        float acc[4][4];
#pragma unroll
        for (int i = 0; i < 4; ++i)
#pragma unroll
            for (int j = 0; j < 4; ++j) acc[i][j] = 0.f;
        for (int kt = 0; kt < C_; kt += 32) {
            __syncthreads();
#pragma unroll
            for (int p = 0; p < 2; ++p) {
                int k = a_k + p * 16;
                float4 af = *(const float4*)(zbase + (size_t)(kt + k) * T_ + a_m);
                *(float4*)&As[k][a_m] = af;
            }
            {
                const float* ep = emb + (size_t)(n0 + b_j) * C_ + kt + b_q;
                float4 e0 = ((const float4*)ep)[0];
                float4 e1 = ((const float4*)ep)[1];
                Bs[b_q + 0][b_j] = e0.x; Bs[b_q + 1][b_j] = e0.y;
                Bs[b_q + 2][b_j] = e0.z; Bs[b_q + 3][b_j] = e0.w;
                Bs[b_q + 4][b_j] = e1.x; Bs[b_q + 5][b_j] = e1.y;
                Bs[b_q + 6][b_j] = e1.z; Bs[b_q + 7][b_j] = e1.w;
            }
            __syncthreads();
#pragma unroll
            for (int k = 0; k < 32; ++k) {
                const float4 a  = *(const float4*)&As[k][ty << 2];
                const float4 bv = *(const float4*)&Bs[k][tx << 2];
                acc[0][0] = fmaf(a.x, bv.x, acc[0][0]);
                acc[0][1] = fmaf(a.x, bv.y, acc[0][1]);
                acc[0][2] = fmaf(a.x, bv.z, acc[0][2]);
                acc[0][3] = fmaf(a.x, bv.w, acc[0][3]);
                acc[1][0] = fmaf(a.y, bv.x, acc[1][0]);
                acc[1][1] = fmaf(a.y, bv.y, acc[1][1]);
                acc[1][2] = fmaf(a.y, bv.z, acc[1][2]);
                acc[1][3] = fmaf(a.y, bv.w, acc[1][3]);
                acc[2][0] = fmaf(a.z, bv.x, acc[2][0]);
                acc[2][1] = fmaf(a.z, bv.y, acc[2][1]);
                acc[2][2] = fmaf(a.z, bv.z, acc[2][2]);
                acc[2][3] = fmaf(a.z, bv.w, acc[2][3]);
                acc[3][0] = fmaf(a.w, bv.x, acc[3][0]);
                acc[3][1] = fmaf(a.w, bv.y, acc[3][1]);
                acc[3][2] = fmaf(a.w, bv.z, acc[3][2]);
                acc[3][3] = fmaf(a.w, bv.w, acc[3][3]);
            }
        }
        const float4 se4 = *(const float4*)(s_e + n0 + (tx << 2));
        const float sev[4] = {se4.x, se4.y, se4.z, se4.w};
#pragma unroll
        for (int j = 0; j < 4; ++j) {
            const int n = n0 + (tx << 2) + j;
#pragma unroll
            for (int i = 0; i < 4; ++i) {
                float A = __fadd_rn(szv[i], sev[j]);
                float s = fmaf(-2.f, acc[i][j], A);
                if (s < v1[i]) { v2[i] = v1[i]; i2[i] = i1[i]; v1[i] = s; i1[i] = n; }
                else if (s < v2[i]) { v2[i] = s; i2[i] = n; }
            }
        }
    }
#pragma unroll
    for (int i = 0; i < 4; ++i) {
        float a1 = v1[i], a2 = v2[i];
        int   y1 = i1[i], y2 = i2[i];
#pragma unroll
        for (int off = 8; off >= 1; off >>= 1) {
            float o1 = __shfl_xor(a1, off, 64); int p1 = __shfl_xor(y1, off, 64);
            float o2 = __shfl_xor(a2, off, 64); int p2 = __shfl_xor(y2, off, 64);
            bool alt = (o1 < a1) || (o1 == a1 && p1 < y1);
            float w1 = alt ? o1 : a1; int q1 = alt ? p1 : y1;
            float lv = alt ? a1 : o1; int lq = alt ? y1 : p1;
            float wv = alt ? o2 : a2; int wq = alt ? p2 : y2;
            bool sb = (lv < wv) || (lv == wv && lq < wq);
            a2 = sb ? lv : wv; y2 = sb ? lq : wq;
            a1 = w1; y1 = q1;
        }
        if (tx == 0) {
            int m = mt * 64 + (ty << 2) + i;
            i1ws[m] = y1;
            i2ws[m] = y2;
        }
    }
}

__global__ __launch_bounds__(256) void vq_pass2_fp32(
        const float* __restrict__ z,
        const float* __restrict__ emb,
        float* __restrict__ ws,
        float* __restrict__ out) {
    const float* s_z = ws + WS_SZ;
    const float* s_e = ws + WS_SE;
    const int* i1ws = (const int*)ws + O_I1;
    const int* i2ws = (const int*)ws + O_I2;
    const int tid  = threadIdx.x;
    const int wave = tid >> 6, lane = tid & 63;
    const int half = lane >> 5;
    const int c0   = (lane & 31) << 3;
    const int rowbase = (blockIdx.x * 4 + wave) * 64;
    for (int r = 0; r < 64; ++r) {
        const int m = rowbase + r;
        int c1 = i1ws[m], c2 = i2ws[m];
        c1 = c1 < 0 ? 0 : (c1 > N_ - 1 ? N_ - 1 : c1);
        c2 = c2 < 0 ? 0 : (c2 > N_ - 1 ? N_ - 1 : c2);
        const int b = m >> 10, t = m & (T_ - 1);
        const float* zp = z + (size_t)b * C_ * T_ + t;
        const int cand = half ? c2 : c1;
        const float* ep = emb + (size_t)cand * C_;
        double sum = 0.0;
#pragma unroll
        for (int c = 0; c < 8; ++c)
            sum = fma((double)zp[(size_t)(c0 + c) * T_], (double)ep[c0 + c], sum);
#pragma unroll
        for (int off = 1; off <= 16; off <<= 1)
            sum += __shfl_xor(sum, off, 64);
        double s1 = __shfl(sum, 0, 64);
        double s2 = __shfl(sum, 32, 64);
        if (lane == 0) {
            float p1 = (float)s1, p2 = (float)s2;
            float d1 = fmaf(-2.f, p1, __fadd_rn(s_z[m], s_e[c1]));
            float d2 = fmaf(-2.f, p2, __fadd_rn(s_z[m], s_e[c2]));
            int win = ((d2 < d1) || (d2 == d1 && c2 < c1)) ? c2 : c1;
            out[OUT_IDX + m] = (float)win;
        }
    }
}

// ---------------- gather z_q (transposed) + loss partial; idx from out ----------------
__global__ __launch_bounds__(256) void vq_gather(
        const float* __restrict__ z,
        const float* __restrict__ emb,
        float* __restrict__ partial,
        float* __restrict__ out) {
    __shared__ float Ls[64][129];
    __shared__ int   idxs[64];
    __shared__ float wred[4];
    const int tid = threadIdx.x;
    const int mg  = blockIdx.x;
    const int m0  = mg << 6;
    const int b   = m0 >> 10;
    const int t0  = m0 & (T_ - 1);
    if (tid < 64) {
        int ix = (int)out[OUT_IDX + m0 + tid];
        idxs[tid] = ix < 0 ? 0 : (ix > N_ - 1 ? N_ - 1 : ix);
    }
    __syncthreads();
    float lsum = 0.f;
    const int w = tid >> 6, l = tid & 63;
    const int tt2 = tid & 63, c0 = tid >> 6;
    const size_t base = (size_t)b * (C_ * T_) + t0 + tt2;
#pragma unroll
    for (int ch = 0; ch < 2; ++ch) {
        __syncthreads();
#pragma unroll
        for (int it = 0; it < 8; ++it) {
            int tt = it * 8 + w * 2 + (l >> 5);
            int cq = l & 31;
            int row = idxs[tt];
            float4 ev = *(const float4*)(emb + (size_t)row * C_ + ch * 128 + (cq << 2));
            Ls[tt][(cq << 2) + 0] = ev.x;
            Ls[tt][(cq << 2) + 1] = ev.y;
            Ls[tt][(cq << 2) + 2] = ev.z;
            Ls[tt][(cq << 2) + 3] = ev.w;
        }
        __syncthreads();
#pragma unroll
        for (int st = 0; st < 32; ++st) {
            int c_l = (st << 2) + c0;
            int c   = (ch << 7) + c_l;
            float v = Ls[tt2][c_l];
            size_t off = base + (size_t)c * T_;
            out[OUT_ZQ + off] = v;
            float d = v - z[off];
            lsum = fmaf(d, d, lsum);
        }
    }
#pragma unroll
    for (int off = 32; off >= 1; off >>= 1) lsum += __shfl_xor(lsum, off, 64);
    if (l == 0) wred[w] = lsum;
    __syncthreads();
    if (tid == 0) partial[mg] = wred[0] + wred[1] + wred[2] + wred[3];
}

__global__ __launch_bounds__(256) void vq_loss(const float* __restrict__ partial,
                                               float* __restrict__ out) {
    __shared__ float wred[4];
    const int tid = threadIdx.x;
    float v = partial[tid];
#pragma unroll
    for (int off = 32; off >= 1; off >>= 1) v += __shfl_xor(v, off, 64);
    if ((tid & 63) == 0) wred[tid >> 6] = v;
    __syncthreads();
    if (tid == 0)
        out[OUT_LOSS] = (wred[0] + wred[1] + wred[2] + wred[3]) * (1.25f / 4194304.f);
}

extern "C" void kernel_launch(void* const* d_in, const int* in_sizes, int n_in,
                              void* d_out, int out_size, void* d_ws, size_t ws_size,
                              hipStream_t stream) {
    const float* z   = (const float*)d_in[0];
    const float* emb = (const float*)d_in[1];
    float* out = (float*)d_out;
    float* ws  = (float*)d_ws;

    if (ws_size >= WS_NEED) {   // fast MFMA path
        char* fb = (char*)d_ws + FB_OFF;
        ull* minima = (ull*)((char*)d_ws + MIN_OFF);
        vq_prep<<<dim3(1024 + (M_ + N_) / 256), dim3(256), 0, stream>>>(z, emb, ws, fb);
        vq_mfma3<<<dim3(256, 2), dim3(256), 0, stream>>>(z, fb, ws + WS_SZ, ws + WS_SE, minima);
        vq_pick2<<<dim3(1024), dim3(256), 0, stream>>>(z, emb, ws, minima, out);
        vq_gather<<<dim3(M_ / 64), dim3(256), 0, stream>>>(z, emb, ws + WS_PART, out);
        vq_loss<<<dim3(1), dim3(256), 0, stream>>>(ws + WS_PART, out);
    } else {                    // round-5 fallback (known-PASS)
        vq_prep<<<dim3(1024 + (M_ + N_) / 256), dim3(256), 0, stream>>>(z, emb, ws, (char*)d_ws + (ws_size > FB_OFF ? FB_OFF : 0));
        vq_pass1_fp32<<<dim3(M_ / 64), dim3(256), 0, stream>>>(z, emb, ws);
        vq_pass2_fp32<<<dim3(64), dim3(256), 0, stream>>>(z, emb, ws, out);
        vq_gather<<<dim3(M_ / 64), dim3(256), 0, stream>>>(z, emb, ws + WS_PART, out);
        vq_loss<<<dim3(1), dim3(256), 0, stream>>>(ws + WS_PART, out);
    }
}

// Round 10
// 519.891 us; speedup vs baseline: 1.0929x; 1.0929x over previous
//
#include <hip/hip_runtime.h>

// VectorQuantizer: z [16,256,1024] fp32, emb [8192,256] fp32.
// out (FP32): [ z_q 4194304 | loss 1 | idx 16384 ]
// Ref emulation: d = fl(fl(s_z+s_e) - 2p), argmin w/ lowest-index ties.
// Fast path: split-bf16 (hi/lo) 32x32x16 MFMA GEMM. A (64m x 256k hi/lo) resident
// in LDS; B double-buffered via async global_load_lds (1 barrier per K16-step).
// Packed-u64 64-col cell minima (128/row) -> top-4 + fp64 fixup (validated).

#define C_    256
#define T_    1024
#define M_    16384
#define N_    8192

#define OUT_ZQ   0
#define OUT_LOSS 4194304
#define OUT_IDX  4194305

// ---- ws layout, fast path ----
#define WS_SZ    0           // s_z [16384] float
#define WS_SE    16384       // s_e [8192] float
#define WS_PART  24576       // loss partials [256] float
#define MIN_OFF  131072u     // bytes: u64 minima [16384 rows][128 cells] = 16 MB
#define FB_OFF   16908288u   // bytes: frag-linear emb hi/lo (32x32x16 layout), 8 MB
#define WS_NEED  25296896u   // bytes (<= 25690112 proven available in R6-R8)
// ---- ws layout, fallback (round-5, known-PASS) ----
#define O_I1     24576
#define O_I2     40960
#define O_PART   73728

typedef __attribute__((ext_vector_type(8)))  short bf16x8;
typedef __attribute__((ext_vector_type(16))) float f32x16;
typedef unsigned long long ull;

__device__ __forceinline__ unsigned short f2b(float f) {
    unsigned u = __float_as_uint(f);
    return (unsigned short)((u + 0x7FFFu + ((u >> 16) & 1u)) >> 16);   // RTNE
}
__device__ __forceinline__ float b2f(unsigned short u) {
    return __uint_as_float(((unsigned)u) << 16);
}
__device__ __forceinline__ void gl_lds16(const void* g, void* l) {
    __builtin_amdgcn_global_load_lds(
        (const __attribute__((address_space(1))) unsigned int*)g,
        (__attribute__((address_space(3))) unsigned int*)l, 16, 0, 0);
}

// ---------------- standalone sums (numpy pairwise replication) ----------------
__global__ __launch_bounds__(256) void vq_sums(const float* __restrict__ z,
                                               const float* __restrict__ emb,
                                               float* __restrict__ ws) {
    int gid = blockIdx.x * 256 + threadIdx.x;
    if (gid < M_) {
        int b = gid >> 10, t = gid & (T_ - 1);
        const float* zp = z + (size_t)b * C_ * T_ + t;
        float blk[2];
#pragma unroll
        for (int h = 0; h < 2; ++h) {
            float r[8];
#pragma unroll
            for (int j = 0; j < 8; ++j) {
                float v = zp[(size_t)(h * 128 + j) * T_];
                r[j] = __fmul_rn(v, v);
            }
            for (int i = 8; i < 128; i += 8)
#pragma unroll
                for (int j = 0; j < 8; ++j) {
                    float v = zp[(size_t)(h * 128 + i + j) * T_];
                    r[j] = __fadd_rn(r[j], __fmul_rn(v, v));
                }
            blk[h] = __fadd_rn(__fadd_rn(__fadd_rn(r[0], r[1]), __fadd_rn(r[2], r[3])),
                               __fadd_rn(__fadd_rn(r[4], r[5]), __fadd_rn(r[6], r[7])));
        }
        ws[WS_SZ + gid] = __fadd_rn(blk[0], blk[1]);
    } else if (gid < M_ + N_) {
        int n = gid - M_;
        const float* ep = emb + (size_t)n * C_;
        float blk[2];
#pragma unroll
        for (int h = 0; h < 2; ++h) {
            float r[8];
#pragma unroll
            for (int j = 0; j < 8; ++j) {
                float v = ep[h * 128 + j];
                r[j] = __fmul_rn(v, v);
            }
            for (int i = 8; i < 128; i += 8)
#pragma unroll
                for (int j = 0; j < 8; ++j) {
                    float v = ep[h * 128 + i + j];
                    r[j] = __fadd_rn(r[j], __fmul_rn(v, v));
                }
            blk[h] = __fadd_rn(__fadd_rn(__fadd_rn(r[0], r[1]), __fadd_rn(r[2], r[3])),
                               __fadd_rn(__fadd_rn(r[4], r[5]), __fadd_rn(r[6], r[7])));
        }
        ws[WS_SE + n] = __fadd_rn(blk[0], blk[1]);
    }
}

// ---------------- fused prep: fb (32x32x16 frag pages) + sums ----------------
// fb page (gnb = n>>5, k16 = k>>4, h): 1 KB; byte = ((n&31) + 32*((k>>3)&1))*16 + (k&7)*2
__global__ __launch_bounds__(256) void vq_prep(const float* __restrict__ z,
                                               const float* __restrict__ emb,
                                               float* __restrict__ ws,
                                               char* __restrict__ fb) {
    const int tid = threadIdx.x;
    if (blockIdx.x < 1024) {            // emb -> fb
        int gid = blockIdx.x * 256 + tid;
        int n = gid >> 5, kg = gid & 31;             // kg = k-oct
        const float* ep = emb + (size_t)n * C_ + kg * 8;
        unsigned hi[8], lo[8];
#pragma unroll
        for (int j = 0; j < 8; ++j) {
            float v = ep[j];
            unsigned short h = f2b(v);
            hi[j] = h;
            lo[j] = f2b(v - b2f(h));
        }
        int gnb = n >> 5, k16 = kg >> 1, k8 = kg & 1;
        int lanep = (n & 31) + (k8 << 5);
        size_t base = ((size_t)((gnb * 16 + k16) * 2) << 10) + (lanep << 4);
        uint4 hv = {hi[0] | (hi[1] << 16), hi[2] | (hi[3] << 16), hi[4] | (hi[5] << 16), hi[6] | (hi[7] << 16)};
        uint4 lv = {lo[0] | (lo[1] << 16), lo[2] | (lo[3] << 16), lo[4] | (lo[5] << 16), lo[6] | (lo[7] << 16)};
        *(uint4*)(fb + base) = hv;
        *(uint4*)(fb + base + 1024) = lv;
    } else {
        int gid = (blockIdx.x - 1024) * 256 + tid;
        if (gid < M_) {
            int b = gid >> 10, t = gid & (T_ - 1);
            const float* zp = z + (size_t)b * C_ * T_ + t;
            float blk[2];
#pragma unroll
            for (int h = 0; h < 2; ++h) {
                float r[8];
#pragma unroll
                for (int j = 0; j < 8; ++j) {
                    float v = zp[(size_t)(h * 128 + j) * T_];
                    r[j] = __fmul_rn(v, v);
                }
                for (int i = 8; i < 128; i += 8)
#pragma unroll
                    for (int j = 0; j < 8; ++j) {
                        float v = zp[(size_t)(h * 128 + i + j) * T_];
                        r[j] = __fadd_rn(r[j], __fmul_rn(v, v));
                    }
                blk[h] = __fadd_rn(__fadd_rn(__fadd_rn(r[0], r[1]), __fadd_rn(r[2], r[3])),
                                   __fadd_rn(__fadd_rn(r[4], r[5]), __fadd_rn(r[6], r[7])));
            }
            ws[WS_SZ + gid] = __fadd_rn(blk[0], blk[1]);
        } else if (gid < M_ + N_) {
            int n = gid - M_;
            const float* ep = emb + (size_t)n * C_;
            float blk[2];
#pragma unroll
            for (int h = 0; h < 2; ++h) {
                float r[8];
#pragma unroll
                for (int j = 0; j < 8; ++j) {
                    float v = ep[h * 128 + j];
                    r[j] = __fmul_rn(v, v);
                }
                for (int i = 8; i < 128; i += 8)
#pragma unroll
                    for (int j = 0; j < 8; ++j) {
                        float v = ep[h * 128 + i + j];
                        r[j] = __fadd_rn(r[j], __fmul_rn(v, v));
                    }
                blk[h] = __fadd_rn(__fadd_rn(__fadd_rn(r[0], r[1]), __fadd_rn(r[2], r[3])),
                                   __fadd_rn(__fadd_rn(r[4], r[5]), __fadd_rn(r[6], r[7])));
            }
            ws[WS_SE + n] = __fadd_rn(blk[0], blk[1]);
        }
    }
}

// ---------------- pass1: 32x32x16 MFMA, A resident, async B dbuf ----------------
// grid 256, block 512 (8 waves). Block tile 64m x 512n per step-group; 256 steps.
__global__ __launch_bounds__(512, 1) void vq_mfma4(
        const float* __restrict__ z, const char* __restrict__ fb,
        const float* __restrict__ sz, const float* __restrict__ se,
        ull* __restrict__ minima) {
    __shared__ __align__(16) char ldsA[65536];   // pages (mt*16+k16)*2+h
    __shared__ __align__(16) char ldsB[65536];   // 2 bufs x 32 pages (nb*2+h)

    const int tid = threadIdx.x;
    const int lane = tid & 63;
    const int w = tid >> 6;                       // wave 0..7 owns 64-col slice
    const int mb = blockIdx.x;

    // ---- one-time A staging: z[b][c][t0..t0+64) -> hi/lo frag pages ----
    {
        const float* zb = z + (size_t)(mb >> 4) * C_ * T_ + ((mb & 15) << 6);
        const int m = tid & 63, co = tid >> 6;
#pragma unroll
        for (int r = 0; r < 4; ++r) {
            const int c_oct = r * 8 + co;          // 0..31
            const int k16 = c_oct >> 1, k8 = c_oct & 1;
            const int lanep = (m & 31) + (k8 << 5);
            const int mt = m >> 5;
            unsigned hi[8], lo[8];
#pragma unroll
            for (int j = 0; j < 8; ++j) {
                float v = zb[(size_t)(c_oct * 8 + j) * T_ + m];
                unsigned short h = f2b(v);
                hi[j] = h;
                lo[j] = f2b(v - b2f(h));
            }
            size_t base = ((size_t)((mt * 16 + k16) * 2) << 10) + (lanep << 4);
            uint4 hv = {hi[0] | (hi[1] << 16), hi[2] | (hi[3] << 16), hi[4] | (hi[5] << 16), hi[6] | (hi[7] << 16)};
            uint4 lv = {lo[0] | (lo[1] << 16), lo[2] | (lo[3] << 16), lo[4] | (lo[5] << 16), lo[6] | (lo[7] << 16)};
            *(uint4*)(ldsA + base) = hv;
            *(uint4*)(ldsA + base + 1024) = lv;
        }
    }

    // s_z per score slot: sl = mt*16 + reg; row = mt*32 + (reg&3)+8*(reg>>2)+4*(lane>>5)
    float szr[32];
#pragma unroll
    for (int mt = 0; mt < 2; ++mt)
#pragma unroll
        for (int r = 0; r < 16; ++r)
            szr[mt * 16 + r] = sz[(mb << 6) + mt * 32 + (r & 3) + 8 * (r >> 2) + 4 * (lane >> 5)];

    ull key[32];
#pragma unroll
    for (int s = 0; s < 32; ++s) key[s] = ~0ULL;

    // issue B loads for step 0 into buf 0
    {
#pragma unroll
        for (int i = 0; i < 4; ++i) {
            const int p = w * 4 + i, nb = p >> 1, h = p & 1;
            const size_t src = ((((size_t)(0 * 128 + 0 * 16 + nb) * 16 + 0) * 2 + h) << 10) + (lane << 4);
            gl_lds16(fb + src, ldsB + (p << 10));
        }
    }
    __syncthreads();

    f32x16 acc[2][2];
    for (int s = 0; s < 256; ++s) {
        const int ns = s >> 7, nt = (s >> 4) & 7, kt = s & 15;
        // prefetch step s+1 into the other buffer (s=255: dead write, unread)
        {
            const int pn = (s + 1 < 256) ? s + 1 : 255;
            const int pns = pn >> 7, pnt = (pn >> 4) & 7, pkt = pn & 15;
            const int buf = (s + 1) & 1;
#pragma unroll
            for (int i = 0; i < 4; ++i) {
                const int p = w * 4 + i, nb = p >> 1, h = p & 1;
                const size_t src = ((((size_t)(pns * 128 + pnt * 16 + nb) * 16 + pkt) * 2 + h) << 10) + (lane << 4);
                gl_lds16(fb + src, ldsB + buf * 32768 + (p << 10));
            }
        }
        if (kt == 0) {
#pragma unroll
            for (int i = 0; i < 2; ++i)
#pragma unroll
                for (int j = 0; j < 2; ++j)
#pragma unroll
                    for (int r = 0; r < 16; ++r) acc[i][j][r] = 0.f;
        }
        {
            const char* bbase = ldsB + (s & 1) * 32768;
            bf16x8 ah[2], al[2], bh[2], bl[2];
#pragma unroll
            for (int mt = 0; mt < 2; ++mt) {
                ah[mt] = *(const bf16x8*)(ldsA + (((mt * 16 + kt) * 2 + 0) << 10) + (lane << 4));
                al[mt] = *(const bf16x8*)(ldsA + (((mt * 16 + kt) * 2 + 1) << 10) + (lane << 4));
            }
#pragma unroll
            for (int nb = 0; nb < 2; ++nb) {
                bh[nb] = *(const bf16x8*)(bbase + (((w * 2 + nb) * 2 + 0) << 10) + (lane << 4));
                bl[nb] = *(const bf16x8*)(bbase + (((w * 2 + nb) * 2 + 1) << 10) + (lane << 4));
            }
#pragma unroll
            for (int nb = 0; nb < 2; ++nb)
#pragma unroll
                for (int mt = 0; mt < 2; ++mt) {
                    f32x16 c = acc[mt][nb];
                    c = __builtin_amdgcn_mfma_f32_32x32x16_bf16(ah[mt], bh[nb], c, 0, 0, 0);
                    c = __builtin_amdgcn_mfma_f32_32x32x16_bf16(ah[mt], bl[nb], c, 0, 0, 0);
                    c = __builtin_amdgcn_mfma_f32_32x32x16_bf16(al[mt], bh[nb], c, 0, 0, 0);
                    acc[mt][nb] = c;
                }
        }
        if (kt == 15) {
            // epilogue: quantized ref-formula score -> key min; flush cell
#pragma unroll
            for (int nb = 0; nb < 2; ++nb) {
                const int ncol = ns * 4096 + nt * 512 + (w * 2 + nb) * 32 + (lane & 31);
                const float sev = se[ncol];
#pragma unroll
                for (int mt = 0; mt < 2; ++mt) {
                    f32x16 c = acc[mt][nb];
#pragma unroll
                    for (int r = 0; r < 16; ++r) {
                        float sc = fmaf(-2.f, c[r], __fadd_rn(szr[mt * 16 + r], sev));
                        ull k = ((ull)__float_as_uint(sc) << 32) | (unsigned)ncol;
                        const int sl = mt * 16 + r;
                        if (k < key[sl]) key[sl] = k;
                    }
                }
            }
            const int cell = ns * 64 + nt * 8 + w;
#pragma unroll
            for (int sl = 0; sl < 32; ++sl) {
                ull kk = key[sl];
#pragma unroll
                for (int off = 1; off <= 16; off <<= 1) {
                    ull o = __shfl_xor(kk, off, 64);
                    if (o < kk) kk = o;
                }
                if ((lane & 31) == 0) {
                    const int r = sl & 15;
                    const int row = (mb << 6) + (sl >> 4) * 32 + (r & 3) + 8 * (r >> 2) + 4 * (lane >> 5);
                    minima[(size_t)row * 128 + cell] = kk;
                }
                key[sl] = ~0ULL;
            }
        }
        __syncthreads();
    }
}

// ---------------- pass2: top-4 of 128 cells + fp64 fixup + idx out ----------------
__global__ __launch_bounds__(256) void vq_pick2(
        const float* __restrict__ z, const float* __restrict__ emb,
        const float* __restrict__ ws, const ull* __restrict__ minima,
        float* __restrict__ out) {
    __shared__ float Lz[256 * 17];
    const float* sz = ws + WS_SZ;
    const float* se = ws + WS_SE;
    const int tid = threadIdx.x;
    const int w = tid >> 6, lane = tid & 63, li = lane & 15;
    const int m0 = blockIdx.x * 16;
    const int b = m0 >> 10, t0 = m0 & (T_ - 1);

    {
        const float* src = z + (size_t)b * C_ * T_ + (size_t)tid * T_ + t0;
#pragma unroll
        for (int u = 0; u < 4; ++u) {
            float4 v = *(const float4*)(src + u * 4);
            Lz[tid * 17 + u * 4 + 0] = v.x;
            Lz[tid * 17 + u * 4 + 1] = v.y;
            Lz[tid * 17 + u * 4 + 2] = v.z;
            Lz[tid * 17 + u * 4 + 3] = v.w;
        }
    }
    __syncthreads();

    for (int rr = 0; rr < 4; ++rr) {
        const int tloc = w * 4 + rr;
        const int m = m0 + tloc;
        ull k0 = minima[(size_t)m * 128 + lane];
        ull k1 = minima[(size_t)m * 128 + 64 + lane];
        int cand[4];
#pragma unroll
        for (int rep = 0; rep < 4; ++rep) {
            ull bf = k0 < k1 ? k0 : k1;
#pragma unroll
            for (int off = 1; off <= 32; off <<= 1) {
                ull o = __shfl_xor(bf, off, 64);
                if (o < bf) bf = o;
            }
            int ix = (int)(unsigned)(bf & 0xFFFFFFFFull);
            cand[rep] = ix < 0 ? 0 : (ix > N_ - 1 ? N_ - 1 : ix);
            if (k0 == bf) k0 = ~0ULL;
            else if (k1 == bf) k1 = ~0ULL;
        }
        const int cn = cand[lane >> 4];
        const float* ep = emb + (size_t)cn * C_;
        double sum = 0.0;
#pragma unroll
        for (int cc = 0; cc < 16; ++cc) {
            int c = cc * 16 + li;
            sum = fma((double)Lz[c * 17 + tloc], (double)ep[c], sum);
        }
#pragma unroll
        for (int off = 1; off <= 8; off <<= 1)
            sum += __shfl_xor(sum, off, 64);
        double s0 = __shfl(sum, 0, 64), s1 = __shfl(sum, 16, 64);
        double s2 = __shfl(sum, 32, 64), s3 = __shfl(sum, 48, 64);
        if (lane == 0) {
            float szm = sz[m];
            float d0 = fmaf(-2.f, (float)s0, __fadd_rn(szm, se[cand[0]]));
            float d1 = fmaf(-2.f, (float)s1, __fadd_rn(szm, se[cand[1]]));
            float d2 = fmaf(-2.f, (float)s2, __fadd_rn(szm, se[cand[2]]));
            float d3 = fmaf(-2.f, (float)s3, __fadd_rn(szm, se[cand[3]]));
            float bd = d0; int bi = cand[0];
            if (d1 < bd || (d1 == bd && cand[1] < bi)) { bd = d1; bi = cand[1]; }
            if (d2 < bd || (d2 == bd && cand[2] < bi)) { bd = d2; bi = cand[2]; }
            if (d3 < bd || (d3 == bd && cand[3] < bi)) { bd = d3; bi = cand[3]; }
            out[OUT_IDX + m] = (float)bi;
        }
    }
}

// ---------------- fallback round-5 pass1/pass2 (known-PASS) ----------------
__global__ __launch_bounds__(256) void vq_pass1_fp32(
        const float* __restrict__ z,
        const float* __restrict__ emb,
        float* __restrict__ ws) {
    __shared__ float As[32][68];
    __shared__ float Bs[32][68];
    const float* s_z = ws + WS_SZ;
    const float* s_e = ws + WS_SE;
    int* i1ws = (int*)ws + O_I1;
    int* i2ws = (int*)ws + O_I2;
    const int tid = threadIdx.x;
    const int mt  = blockIdx.x;
    const int tx  = tid & 15, ty = tid >> 4;
    const int b   = mt >> 4;
    const int t0  = (mt << 6) & (T_ - 1);
    const float* zbase = z + (size_t)b * C_ * T_ + t0;
    const int a_k = tid >> 4;
    const int a_m = (tid & 15) << 2;
    const int b_j = tid >> 2;
    const int b_q = (tid & 3) << 3;
    const float4 sz4 = *(const float4*)(s_z + mt * 64 + (ty << 2));
    const float szv[4] = {sz4.x, sz4.y, sz4.z, sz4.w};
    float v1[4], v2[4];
    int   i1[4], i2[4];
#pragma unroll
    for (int i = 0; i < 4; ++i) {
        v1[i] = INFINITY; v2[i] = INFINITY;
        i1[i] = 0x7FFFFFFF; i2[i] = 0x7FFFFFFF;
    }
    for (int nt = 0; nt < N_ / 64; ++nt) {
        const int n0 = nt * 64;
        float acc[4][4];
#pragma unroll
        for (int i = 0; i < 4; ++i)
#pragma unroll
            for (int j = 0; j < 4; ++j) acc[i][j] = 0.f;
        for (int kt = 0; kt < C_; kt += 32) {
            __syncthreads();
#pragma unroll
            for (int p = 0; p < 2; ++p) {
                int k = a_k + p * 16;
                float4 af = *(const float4*)(zbase + (size_t)(kt + k) * T_ + a_m);
                *(float4*)&As[k][a_m] = af;
            }
            {
                const float* ep = emb + (size_t)(n0 + b_j) * C_ + kt + b_q;
                float4 e0 = ((const float4*)ep)[0];
                float4 e1 = ((const float4*)ep)[1];
                Bs[b_q + 0][b_j] = e0.x; Bs[b_q + 1][b_j] = e0.y;
                Bs[b_q + 2][b_j] = e0.z; Bs[b_q + 3][b_j] = e0.w;
                Bs[b_q + 4][b_j] = e1.x; Bs[b_q + 5][b_j] = e1.y;
                Bs[b_q + 6][b_j] = e1.z; Bs[b_q + 7][b_j] = e1.w;
            }
            __syncthreads();
#pragma unroll
            for (int k = 0; k < 32; ++k) {
                const float4 a  = *(const float4*)&As[k][ty << 2];
                const float4 bv = *(const float4*)&Bs[k][tx << 2];
                acc[0][0] = fmaf(a.x, bv.x, acc[0][0]);
                acc[0][1] = fmaf(a.x, bv.y, acc[0][1]);
                acc[0][2] = fmaf(a.x, bv.z, acc[0][2]);
                acc[0][3] = fmaf(a.x, bv.w, acc[0][3]);
                acc[1][0] = fmaf(a.y, bv.x, acc[1][0]);
                acc[1][1] = fmaf(a.y, bv.y, acc[1][1]);
                acc[1][2] = fmaf(a.y, bv.z, acc[1][2]);
                acc[1][3] = fmaf(a.y, bv.w, acc[1][3]);
                acc[2][0] = fmaf(a.z, bv.x, acc[2][0]);
                acc[2][1] = fmaf(a.z, bv.y, acc[2][1]);
                acc[2][2] = fmaf(a.z, bv.z, acc[2][2]);
                acc[2][3] = fmaf(a.z, bv.w, acc[2][3]);
                acc[3][0] = fmaf(a.w, bv.x, acc[3][0]);
                acc[3][1] = fmaf(a.w, bv.y, acc[3][1]);
                acc[3][2] = fmaf(a.w, bv.z, acc[3][2]);
                acc[3][3] = fmaf(a.w, bv.w, acc[3][3]);
            }
        }
        const float4 se4 = *(const float4*)(s_e + n0 + (tx << 2));
        const float sev[4] = {se4.x, se4.y, se4.z, se4.w};
#pragma unroll
        for (int j = 0; j < 4; ++j) {
            const int n = n0 + (tx << 2) + j;
#pragma unroll
            for (int i = 0; i < 4; ++i) {
                float A = __fadd_rn(szv[i], sev[j]);
                float s = fmaf(-2.f, acc[i][j], A);
                if (s < v1[i]) { v2[i] = v1[i]; i2[i] = i1[i]; v1[i] = s; i1[i] = n; }
                else if (s < v2[i]) { v2[i] = s; i2[i] = n; }
            }
        }
    }
#pragma unroll
    for (int i = 0; i < 4; ++i) {
        float a1 = v1[i], a2 = v2[i];
        int   y1 = i1[i], y2 = i2[i];
#pragma unroll
        for (int off = 8; off >= 1; off >>= 1) {
            float o1 = __shfl_xor(a1, off, 64); int p1 = __shfl_xor(y1, off, 64);
            float o2 = __shfl_xor(a2, off, 64); int p2 = __shfl_xor(y2, off, 64);
            bool alt = (o1 < a1) || (o1 == a1 && p1 < y1);
            float w1 = alt ? o1 : a1; int q1 = alt ? p1 : y1;
            float lv = alt ? a1 : o1; int lq = alt ? y1 : p1;
            float wv = alt ? o2 : a2; int wq = alt ? p2 : y2;
            bool sb = (lv < wv) || (lv == wv && lq < wq);
            a2 = sb ? lv : wv; y2 = sb ? lq : wq;
            a1 = w1; y1 = q1;
        }
        if (tx == 0) {
            int m = mt * 64 + (ty << 2) + i;
            i1ws[m] = y1;
            i2ws[m] = y2;
        }
    }
}

__global__ __launch_bounds__(256) void vq_pass2_fp32(
        const float* __restrict__ z,
        const float* __restrict__ emb,
        float* __restrict__ ws,
        float* __restrict__ out) {
    const float* s_z = ws + WS_SZ;
    const float* s_e = ws + WS_SE;
    const int* i1ws = (const int*)ws + O_I1;
    const int* i2ws = (const int*)ws + O_I2;
    const int tid  = threadIdx.x;
    const int wave = tid >> 6, lane = tid & 63;
    const int half = lane >> 5;
    const int c0   = (lane & 31) << 3;
    const int rowbase = (blockIdx.x * 4 + wave) * 64;
    for (int r = 0; r < 64; ++r) {
        const int m = rowbase + r;
        int c1 = i1ws[m], c2 = i2ws[m];
        c1 = c1 < 0 ? 0 : (c1 > N_ - 1 ? N_ - 1 : c1);
        c2 = c2 < 0 ? 0 : (c2 > N_ - 1 ? N_ - 1 : c2);
        const int b = m >> 10, t = m & (T_ - 1);
        const float* zp = z + (size_t)b * C_ * T_ + t;
        const int cand = half ? c2 : c1;
        const float* ep = emb + (size_t)cand * C_;
        double sum = 0.0;
#pragma unroll
        for (int c = 0; c < 8; ++c)
            sum = fma((double)zp[(size_t)(c0 + c) * T_], (double)ep[c0 + c], sum);
#pragma unroll
        for (int off = 1; off <= 16; off <<= 1)
            sum += __shfl_xor(sum, off, 64);
        double s1 = __shfl(sum, 0, 64);
        double s2 = __shfl(sum, 32, 64);
        if (lane == 0) {
            float p1 = (float)s1, p2 = (float)s2;
            float d1 = fmaf(-2.f, p1, __fadd_rn(s_z[m], s_e[c1]));
            float d2 = fmaf(-2.f, p2, __fadd_rn(s_z[m], s_e[c2]));
            int win = ((d2 < d1) || (d2 == d1 && c2 < c1)) ? c2 : c1;
            out[OUT_IDX + m] = (float)win;
        }
    }
}

// ---------------- gather z_q (transposed) + loss partial; idx from out ----------------
__global__ __launch_bounds__(256) void vq_gather(
        const float* __restrict__ z,
        const float* __restrict__ emb,
        float* __restrict__ partial,
        float* __restrict__ out) {
    __shared__ float Ls[64][129];
    __shared__ int   idxs[64];
    __shared__ float wred[4];
    const int tid = threadIdx.x;
    const int mg  = blockIdx.x;
    const int m0  = mg << 6;
    const int b   = m0 >> 10;
    const int t0  = m0 & (T_ - 1);
    if (tid < 64) {
        int ix = (int)out[OUT_IDX + m0 + tid];
        idxs[tid] = ix < 0 ? 0 : (ix > N_ - 1 ? N_ - 1 : ix);
    }
    __syncthreads();
    float lsum = 0.f;
    const int w = tid >> 6, l = tid & 63;
    const int tt2 = tid & 63, c0 = tid >> 6;
    const size_t base = (size_t)b * (C_ * T_) + t0 + tt2;
#pragma unroll
    for (int ch = 0; ch < 2; ++ch) {
        __syncthreads();
#pragma unroll
        for (int it = 0; it < 8; ++it) {
            int tt = it * 8 + w * 2 + (l >> 5);
            int cq = l & 31;
            int row = idxs[tt];
            float4 ev = *(const float4*)(emb + (size_t)row * C_ + ch * 128 + (cq << 2));
            Ls[tt][(cq << 2) + 0] = ev.x;
            Ls[tt][(cq << 2) + 1] = ev.y;
            Ls[tt][(cq << 2) + 2] = ev.z;
            Ls[tt][(cq << 2) + 3] = ev.w;
        }
        __syncthreads();
#pragma unroll
        for (int st = 0; st < 32; ++st) {
            int c_l = (st << 2) + c0;
            int c   = (ch << 7) + c_l;
            float v = Ls[tt2][c_l];
            size_t off = base + (size_t)c * T_;
            out[OUT_ZQ + off] = v;
            float d = v - z[off];
            lsum = fmaf(d, d, lsum);
        }
    }
#pragma unroll
    for (int off = 32; off >= 1; off >>= 1) lsum += __shfl_xor(lsum, off, 64);
    if (l == 0) wred[w] = lsum;
    __syncthreads();
    if (tid == 0) partial[mg] = wred[0] + wred[1] + wred[2] + wred[3];
}

__global__ __launch_bounds__(256) void vq_loss(const float* __restrict__ partial,
                                               float* __restrict__ out) {
    __shared__ float wred[4];
    const int tid = threadIdx.x;
    float v = partial[tid];
#pragma unroll
    for (int off = 32; off >= 1; off >>= 1) v += __shfl_xor(v, off, 64);
    if ((tid & 63) == 0) wred[tid >> 6] = v;
    __syncthreads();
    if (tid == 0)
        out[OUT_LOSS] = (wred[0] + wred[1] + wred[2] + wred[3]) * (1.25f / 4194304.f);
}

extern "C" void kernel_launch(void* const* d_in, const int* in_sizes, int n_in,
                              void* d_out, int out_size, void* d_ws, size_t ws_size,
                              hipStream_t stream) {
    const float* z   = (const float*)d_in[0];
    const float* emb = (const float*)d_in[1];
    float* out = (float*)d_out;
    float* ws  = (float*)d_ws;

    if (ws_size >= WS_NEED) {   // fast MFMA path
        char* fb = (char*)d_ws + FB_OFF;
        ull* minima = (ull*)((char*)d_ws + MIN_OFF);
        vq_prep<<<dim3(1024 + (M_ + N_) / 256), dim3(256), 0, stream>>>(z, emb, ws, fb);
        vq_mfma4<<<dim3(256), dim3(512), 0, stream>>>(z, fb, ws + WS_SZ, ws + WS_SE, minima);
        vq_pick2<<<dim3(1024), dim3(256), 0, stream>>>(z, emb, ws, minima, out);
        vq_gather<<<dim3(M_ / 64), dim3(256), 0, stream>>>(z, emb, ws + WS_PART, out);
        vq_loss<<<dim3(1), dim3(256), 0, stream>>>(ws + WS_PART, out);
    } else {                    // round-5 fallback (known-PASS)
        vq_sums<<<dim3((M_ + N_) / 256), dim3(256), 0, stream>>>(z, emb, ws);
        vq_pass1_fp32<<<dim3(M_ / 64), dim3(256), 0, stream>>>(z, emb, ws);
        vq_pass2_fp32<<<dim3(64), dim3(256), 0, stream>>>(z, emb, ws, out);
        vq_gather<<<dim3(M_ / 64), dim3(256), 0, stream>>>(z, emb, ws + O_PART, out);
        vq_loss<<<dim3(1), dim3(256), 0, stream>>>(ws + O_PART, out);
    }
}